// Round 7
// baseline (3558.416 us; speedup 1.0000x reference)
//
#include <hip/hip_runtime.h>

typedef unsigned short u16;
typedef unsigned long long u64;
typedef short v8s __attribute__((ext_vector_type(8)));
typedef float v4f __attribute__((ext_vector_type(4)));
typedef unsigned v2u __attribute__((ext_vector_type(2)));

#define Bb 256
#define Tt 512
#define Dd 64
#define Hh 512
#define G4 2048

#define NGROUP 16    // batch groups (16 batch each), static mapping
#define NCHUNK 16    // hidden chunks per group (32 hidden units each)
#define BT 16
#define HC 32
#define NCOL 128     // local gate cols = 4 gates * HC

#define WHH_S 520   // 512 + 8 pad (bf16 elems), 1040 B row = 16B-aligned
#define WIH_S 72    // 64 + 8 pad
#define SMEM_BYTES (NCOL*WHH_S*2 + NCOL*WIH_S*2)   // 151552 -> 1 block/CU

#define MFMA(a,b,c) __builtin_amdgcn_mfma_f32_16x16x32_bf16((a),(b),(c),0,0,0)

__device__ __forceinline__ u16 f2bf(float f) {
  unsigned u = __float_as_uint(f);
  unsigned r = (u + 0x7fffu + ((u >> 16) & 1u)) >> 16;
  return (u16)r;
}
__device__ __forceinline__ float bf2f(u16 v) {
  return __uint_as_float(((unsigned)v) << 16);
}
__device__ __forceinline__ float sigm(float x) { return 1.0f / (1.0f + __expf(-x)); }
__device__ __forceinline__ float tanh_f(float x) {
  float a = fabsf(x);
  float e = __expf(-2.0f * a);
  float r = (1.0f - e) / (1.0f + e);
  return copysignf(r, x);
}
__device__ __forceinline__ float softplus_f(float x) { return log1pf(__expf(x)); }

// L3-coherent flag load (L1/L2 bypass): one 64B line holds all 16 flags.
__device__ __forceinline__ unsigned ld_flag_l3(const unsigned* p) {
  unsigned v;
  asm volatile("global_load_dword %0, %1, off sc0 sc1\n\ts_waitcnt vmcnt(0)"
               : "=v"(v) : "v"(p) : "memory");
  return v;
}

// ---------------------------------------------------------------- prep:
// x fp32 [B][T][D] -> bf16 [T][B][D]; zero sync flags.
__global__ void k_prep(const float* __restrict__ x, u16* __restrict__ x_bf,
                       unsigned* __restrict__ flags)
{
  if (blockIdx.x == 0 && threadIdx.x < NGROUP * NCHUNK) flags[threadIdx.x] = 0u;
  const int N4 = Tt * Bb * Dd / 4;
  int stride = gridDim.x * blockDim.x;
  for (int i = blockIdx.x * blockDim.x + threadIdx.x; i < N4; i += stride) {
    int idx = i * 4;
    int t = idx >> 14;          // / (B*D)
    int rem = idx & 16383;
    int b = rem >> 6;
    int d = rem & 63;
    float4 v = *(const float4*)(x + (size_t)b * (Tt * Dd) + t * Dd + d);
    unsigned lo = (unsigned)f2bf(v.x) | ((unsigned)f2bf(v.y) << 16);
    unsigned hi = (unsigned)f2bf(v.z) | ((unsigned)f2bf(v.w) << 16);
    *(uint2*)(x_bf + idx) = make_uint2(lo, hi);
  }
}

// ---------------------------------------------------------------- main:
// persistent LSTM. 256 blocks x 64 threads (ONE wave per block):
// 16 batch groups (16 batch) x 16 hidden chunks (32 hidden = 128 gate
// cols, 148 KB sampled weights in LDS). Static group/chunk from blockIdx
// (no placement assumptions). h exchange via L3 (sc0 sc1): total sc read
// = 4 MB/step (halved vs NCHUNK=32). Single-wave block => NO barriers in
// the step loop; poll exits via __all over one 64B flag line. Transposed
// MFMA: lane owns 8 hidden x 1 batch, all gates -> in-register update.
__global__ __launch_bounds__(64, 1) void lstm_main(
    const float* __restrict__ whh_mu, const float* __restrict__ whh_rho, const float* __restrict__ whh_eps,
    const float* __restrict__ wih_mu, const float* __restrict__ wih_rho, const float* __restrict__ wih_eps,
    const float* __restrict__ b_mu,  const float* __restrict__ b_rho,  const float* __restrict__ b_eps,
    const u16* __restrict__ x_bf, u16* __restrict__ h_buf, unsigned* __restrict__ flags)
{
  extern __shared__ char smem[];
  u16* w_hh_lds = (u16*)smem;                 // [NCOL][WHH_S]
  u16* w_ih_lds = w_hh_lds + NCOL * WHH_S;    // [NCOL][WIH_S]

  const int tid   = threadIdx.x;
  const int g     = blockIdx.x & 15;   // batch group (static)
  const int chunk = blockIdx.x >> 4;   // hidden chunk (static)
  const int b0    = g * BT;
  const int j0    = chunk * HC;

  // ---- sample weight chunk into LDS. local col lc = gate*32 + jj
  for (int h2 = 0; h2 < 2; ++h2) {
    const int lc = h2 * 64 + tid;                      // 0..127
    const int gcol = (lc >> 5) * Hh + j0 + (lc & 31);  // global gate column
    for (int k = 0; k < Hh; ++k) {
      int gi = k * G4 + gcol;
      float w = whh_mu[gi] + softplus_f(whh_rho[gi]) * whh_eps[gi];
      w_hh_lds[lc * WHH_S + k] = f2bf(w);
    }
    for (int k = 0; k < Dd; ++k) {
      int gi = k * G4 + gcol;
      float w = wih_mu[gi] + softplus_f(wih_rho[gi]) * wih_eps[gi];
      w_ih_lds[lc * WIH_S + k] = f2bf(w);
    }
  }

  // ---- MFMA geometry (transposed: A=weights from LDS, B=h/x from global)
  const int ln = tid & 15;
  const int q  = tid >> 4;
  const int ko = q * 8;

  const u16* Wh[8]; const u16* Wx[8];
  #pragma unroll
  for (int rt = 0; rt < 8; ++rt) {
    Wh[rt] = w_hh_lds + (rt * 16 + ln) * WHH_S + ko;
    Wx[rt] = w_ih_lds + (rt * 16 + ln) * WIH_S + ko;
  }

  const int bat = b0 + ln;   // this lane's batch row (B-operand col)

  // ---- per-lane biases: lane owns hidden jj = half*16 + q*4 + r (8 units)
  float bs[4][2][4];   // [gate][half][r]
  #pragma unroll
  for (int gt = 0; gt < 4; ++gt)
    #pragma unroll
    for (int hf = 0; hf < 2; ++hf)
      #pragma unroll
      for (int r = 0; r < 4; ++r) {
        int colg = gt * Hh + j0 + hf * 16 + q * 4 + r;
        bs[gt][hf][r] = b_mu[colg] + softplus_f(b_rho[colg]) * b_eps[colg];
      }

  float cc[8] = {0.f,0.f,0.f,0.f,0.f,0.f,0.f,0.f};  // cell state per hidden
  unsigned* const fgrp = flags + g * NCHUNK;        // 16 flags = one 64B line
  __syncthreads();   // weights-in-LDS ready (one-time)

  for (int t = 0; t < Tt; ++t) {
    v4f acc[8];
    #pragma unroll
    for (int rt = 0; rt < 8; ++rt) acc[rt] = (v4f){0.f,0.f,0.f,0.f};

    // ---- input projection first (h-independent)
    {
      const u16* xb = x_bf + (size_t)t * (Bb * Dd) + bat * Dd + ko;
      #pragma unroll
      for (int ks = 0; ks < 2; ++ks) {
        v8s xf = *(const v8s*)(xb + ks * 32);
        #pragma unroll
        for (int rt = 0; rt < 8; ++rt)
          acc[rt] = MFMA(*(const v8s*)(Wx[rt] + ks * 32), xf, acc[rt]);
      }
    }

    if (t > 0) {
      // ---- poll: all 16 chunks of this group published h_t. One wave,
      // lanes poll flags[tid&15] (single 64B line); uniform exit via __all.
      const unsigned* fp = &fgrp[tid & 15];
      for (;;) {
        unsigned v = ld_flag_l3(fp);
        if (__all((int)(v >= (unsigned)t))) break;
      }

      // ---- recurrent GEMM, K=512: 16 sc loads in flight, one drain.
      // waitcnt asm has NO memory clobber so the compiler may overlap the
      // (independent) weight ds_reads with the load drain; Ahh ties pin
      // the MFMA ordering.
      const u16* hb = h_buf + (t & 1) * (Bb * Hh) + bat * Hh + ko;
      v8s Ahh[16];
      #pragma unroll
      for (int ks = 0; ks < 16; ++ks) {
        asm volatile("global_load_dwordx4 %0, %1, off offset:%c2 sc0 sc1"
                     : "=v"(Ahh[ks]) : "v"(hb), "i"(ks * 64));
      }
      asm volatile("s_waitcnt vmcnt(0)");
      #pragma unroll
      for (int ks = 0; ks < 16; ++ks) {
        asm volatile("" : "+v"(Ahh[ks]));
      }
      #pragma unroll
      for (int ks = 0; ks < 16; ++ks) {
        #pragma unroll
        for (int rt = 0; rt < 8; ++rt)
          acc[rt] = MFMA(*(const v8s*)(Wh[rt] + ks * 32), Ahh[ks], acc[rt]);
      }
    }

    // ---- LSTM update fully in-register: tile rt = gate*2 + half;
    // lane owns batch bat, hidden jj = half*16 + q*4 + r.
    {
      u16* hn = h_buf + ((t + 1) & 1) * (Bb * Hh) + bat * Hh + j0;
      #pragma unroll
      for (int hf = 0; hf < 2; ++hf) {
        u16 hv[4];
        #pragma unroll
        for (int r = 0; r < 4; ++r) {
          float ig = sigm  (acc[0 + hf][r] + bs[0][hf][r]);
          float fg = sigm  (acc[2 + hf][r] + bs[1][hf][r]);
          float gg = tanh_f(acc[4 + hf][r] + bs[2][hf][r]);
          float og = sigm  (acc[6 + hf][r] + bs[3][hf][r]);
          int ci = hf * 4 + r;
          cc[ci] = fg * cc[ci] + ig * gg;
          hv[r] = f2bf(og * tanh_f(cc[ci]));
        }
        v2u qv;
        qv[0] = (unsigned)hv[0] | ((unsigned)hv[1] << 16);
        qv[1] = (unsigned)hv[2] | ((unsigned)hv[3] << 16);
        u16* hp = hn + hf * 16 + q * 4;
        asm volatile("global_store_dwordx2 %0, %1, off sc0 sc1"
                     :: "v"(hp), "v"(qv) : "memory");
      }
    }

    // ---- publish: drain h stores (wave-wide), lane 0 sets flag (L3).
    // Single wave => no barrier; volatile-asm order pins store->drain->flag.
    asm volatile("s_waitcnt vmcnt(0)" ::: "memory");
    if (tid == 0) {
      unsigned tv = (unsigned)(t + 1);
      unsigned* fp = &fgrp[chunk];
      asm volatile("global_store_dword %0, %1, off sc0 sc1"
                   :: "v"(fp), "v"(tv) : "memory");
    }
  }
}

// ---------------------------------------------------------------- epilogue:
// out[b] = h_last[b,:] . lin_w + lin_b   (h_last in h_buf[0], since T even)
__global__ void k_out(const u16* __restrict__ h, const float* __restrict__ lw,
                      const float* __restrict__ lb, float* __restrict__ out)
{
  int b = blockIdx.x * 64 + threadIdx.x;
  if (b >= Bb) return;
  const u16* hr = h + b * Hh;
  float acc = 0.f;
  #pragma unroll 8
  for (int k = 0; k < Hh; ++k) acc += bf2f(hr[k]) * lw[k];
  out[b] = acc + lb[0];
}

extern "C" void kernel_launch(void* const* d_in, const int* in_sizes, int n_in,
                              void* d_out, int out_size, void* d_ws, size_t ws_size,
                              hipStream_t stream)
{
  (void)in_sizes; (void)n_in; (void)out_size; (void)ws_size;
  const float* x       = (const float*)d_in[0];
  const float* wih_mu  = (const float*)d_in[1];
  const float* wih_rho = (const float*)d_in[2];
  const float* wih_eps = (const float*)d_in[3];
  const float* whh_mu  = (const float*)d_in[4];
  const float* whh_rho = (const float*)d_in[5];
  const float* whh_eps = (const float*)d_in[6];
  const float* b_mu    = (const float*)d_in[7];
  const float* b_rho   = (const float*)d_in[8];
  const float* b_eps   = (const float*)d_in[9];
  const float* lin_w   = (const float*)d_in[10];
  const float* lin_b   = (const float*)d_in[11];
  float* out = (float*)d_out;

  // workspace layout
  u16* x_bf  = (u16*)d_ws;                       // T*B*D bf16  = 16 MB
  u16* h_buf = x_bf + (size_t)Tt * Bb * Dd;      // 2*B*H bf16  = 512 KB
  unsigned* flags = (unsigned*)(h_buf + 2 * Bb * Hh);  // 256 flags

  k_prep<<<2048, 256, 0, stream>>>(x, x_bf, flags);

  hipFuncSetAttribute(reinterpret_cast<const void*>(lstm_main),
                      hipFuncAttributeMaxDynamicSharedMemorySize, SMEM_BYTES);
  lstm_main<<<NGROUP * NCHUNK, 64, SMEM_BYTES, stream>>>(
      whh_mu, whh_rho, whh_eps, wih_mu, wih_rho, wih_eps,
      b_mu, b_rho, b_eps, x_bf, h_buf, flags);

  k_out<<<(Bb + 63) / 64, 64, 0, stream>>>(h_buf, lin_w, lin_b, out);
}

// Round 8
// 3051.268 us; speedup vs baseline: 1.1662x; 1.1662x over previous
//
#include <hip/hip_runtime.h>

typedef unsigned short u16;
typedef unsigned long long u64;
typedef short v8s __attribute__((ext_vector_type(8)));
typedef float v4f __attribute__((ext_vector_type(4)));
typedef unsigned v2u __attribute__((ext_vector_type(2)));

#define Bb 256
#define Tt 512
#define Dd 64
#define Hh 512
#define G4 2048

#define NGROUP 16    // batch groups (16 batch each), static mapping
#define NCHUNK 16    // hidden chunks per group (32 hidden units each)
#define BT 16
#define HC 32
#define NCOL 128     // local gate cols = 4 gates * HC

#define WHH_S 520   // 512 + 8 pad (bf16 elems)
#define WIH_S 72    // 64 + 8 pad
// weights 151552 B + 8 KB reduce buffer = 159744 <= 163840 -> 1 block/CU
#define SMEM_BYTES (NCOL*WHH_S*2 + NCOL*WIH_S*2 + 8192)

#define MFMA(a,b,c) __builtin_amdgcn_mfma_f32_16x16x32_bf16((a),(b),(c),0,0,0)

__device__ __forceinline__ u16 f2bf(float f) {
  unsigned u = __float_as_uint(f);
  unsigned r = (u + 0x7fffu + ((u >> 16) & 1u)) >> 16;
  return (u16)r;
}
__device__ __forceinline__ float bf2f(u16 v) {
  return __uint_as_float(((unsigned)v) << 16);
}
__device__ __forceinline__ float sigm(float x) { return 1.0f / (1.0f + __expf(-x)); }
__device__ __forceinline__ float tanh_f(float x) {
  float a = fabsf(x);
  float e = __expf(-2.0f * a);
  float r = (1.0f - e) / (1.0f + e);
  return copysignf(r, x);
}
__device__ __forceinline__ float softplus_f(float x) { return log1pf(__expf(x)); }

// L3-coherent flag load (L1/L2 bypass): one 64B line holds all 16 flags.
__device__ __forceinline__ unsigned ld_flag_l3(const unsigned* p) {
  unsigned v;
  asm volatile("global_load_dword %0, %1, off sc0 sc1\n\ts_waitcnt vmcnt(0)"
               : "=v"(v) : "v"(p) : "memory");
  return v;
}

// ---------------------------------------------------------------- prep:
// x fp32 [B][T][D] -> bf16 [T][B][D]; zero sync flags.
__global__ void k_prep(const float* __restrict__ x, u16* __restrict__ x_bf,
                       unsigned* __restrict__ flags)
{
  if (blockIdx.x == 0 && threadIdx.x < NGROUP * NCHUNK) flags[threadIdx.x] = 0u;
  const int N4 = Tt * Bb * Dd / 4;
  int stride = gridDim.x * blockDim.x;
  for (int i = blockIdx.x * blockDim.x + threadIdx.x; i < N4; i += stride) {
    int idx = i * 4;
    int t = idx >> 14;          // / (B*D)
    int rem = idx & 16383;
    int b = rem >> 6;
    int d = rem & 63;
    float4 v = *(const float4*)(x + (size_t)b * (Tt * Dd) + t * Dd + d);
    unsigned lo = (unsigned)f2bf(v.x) | ((unsigned)f2bf(v.y) << 16);
    unsigned hi = (unsigned)f2bf(v.z) | ((unsigned)f2bf(v.w) << 16);
    *(uint2*)(x_bf + idx) = make_uint2(lo, hi);
  }
}

// ---------------------------------------------------------------- main:
// persistent LSTM. 256 blocks x 128 thr (2 waves), static group/chunk.
// NCHUNK=16 => sc h-read = 4 MB/step (the bf16-weights-in-LDS minimum).
// K-SPLIT across waves: wave wv handles k in [wv*256,(wv+1)*256) -> zero
// duplicate h loads; partial accumulators reduced via 8 KB LDS buffer.
// Barrier placement lets wave 1 run ahead (next x-proj + poll) while
// wave 0 does update/store/drain/publish. h/flag exchange via L3
// (sc0 sc1): correct regardless of block placement, no cache maintenance.
__global__ __launch_bounds__(128, 1) void lstm_main(
    const float* __restrict__ whh_mu, const float* __restrict__ whh_rho, const float* __restrict__ whh_eps,
    const float* __restrict__ wih_mu, const float* __restrict__ wih_rho, const float* __restrict__ wih_eps,
    const float* __restrict__ b_mu,  const float* __restrict__ b_rho,  const float* __restrict__ b_eps,
    const u16* __restrict__ x_bf, u16* __restrict__ h_buf, unsigned* __restrict__ flags)
{
  extern __shared__ char smem[];
  u16* w_hh_lds = (u16*)smem;                 // [NCOL][WHH_S]
  u16* w_ih_lds = w_hh_lds + NCOL * WHH_S;    // [NCOL][WIH_S]
  v4f* red      = (v4f*)(w_ih_lds + NCOL * WIH_S);  // [8][64] partials

  const int tid   = threadIdx.x;
  const int g     = blockIdx.x & 15;   // batch group (static)
  const int chunk = blockIdx.x >> 4;   // hidden chunk (static)
  const int b0    = g * BT;
  const int j0    = chunk * HC;

  // ---- sample weight chunk into LDS: one column per thread (128 cols)
  {
    const int lc = tid;                                // 0..127
    const int gcol = (lc >> 5) * Hh + j0 + (lc & 31);  // global gate column
    #pragma unroll 4
    for (int k = 0; k < Hh; ++k) {
      int gi = k * G4 + gcol;
      float w = whh_mu[gi] + softplus_f(whh_rho[gi]) * whh_eps[gi];
      w_hh_lds[lc * WHH_S + k] = f2bf(w);
    }
    #pragma unroll 4
    for (int k = 0; k < Dd; ++k) {
      int gi = k * G4 + gcol;
      float w = wih_mu[gi] + softplus_f(wih_rho[gi]) * wih_eps[gi];
      w_ih_lds[lc * WIH_S + k] = f2bf(w);
    }
  }

  // ---- geometry: wave wv owns K half [wv*256, wv*256+256)
  const int lane  = tid & 63;
  const int wv    = tid >> 6;
  const int ln    = lane & 15;
  const int q     = lane >> 4;
  const int ko    = q * 8;
  const int kbase = wv * 256;

  const u16* Wh[8]; const u16* Wx[8];
  #pragma unroll
  for (int rt = 0; rt < 8; ++rt) {
    Wh[rt] = w_hh_lds + (rt * 16 + ln) * WHH_S + kbase + ko;
    Wx[rt] = w_ih_lds + (rt * 16 + ln) * WIH_S + wv * 32 + ko;
  }

  const int bat = b0 + ln;   // this lane's batch row (B-operand col)

  // ---- biases + cell state live on wave 0 only (it does the update)
  float bs[4][2][4];
  float cc[8] = {0.f,0.f,0.f,0.f,0.f,0.f,0.f,0.f};
  if (wv == 0) {
    #pragma unroll
    for (int gt = 0; gt < 4; ++gt)
      #pragma unroll
      for (int hf = 0; hf < 2; ++hf)
        #pragma unroll
        for (int r = 0; r < 4; ++r) {
          int colg = gt * Hh + j0 + hf * 16 + q * 4 + r;
          bs[gt][hf][r] = b_mu[colg] + softplus_f(b_rho[colg]) * b_eps[colg];
        }
  }

  unsigned* const fgrp = flags + g * NCHUNK;   // 16 flags = one 64B line
  __syncthreads();   // weights-in-LDS ready (one-time)

  for (int t = 0; t < Tt; ++t) {
    v4f acc[8];
    #pragma unroll
    for (int rt = 0; rt < 8; ++rt) acc[rt] = (v4f){0.f,0.f,0.f,0.f};

    // ---- input projection (this wave's K-half of D=64: one ks slice)
    {
      const u16* xb = x_bf + (size_t)t * (Bb * Dd) + bat * Dd + wv * 32 + ko;
      v8s xf = *(const v8s*)xb;
      #pragma unroll
      for (int rt = 0; rt < 8; ++rt)
        acc[rt] = MFMA(*(const v8s*)Wx[rt], xf, acc[rt]);
    }

    if (t > 0) {
      // ---- poll: all 16 chunks of this group published h_t
      const unsigned* fp = &fgrp[lane & 15];
      for (;;) {
        unsigned v = ld_flag_l3(fp);
        if (__all((int)(v >= (unsigned)t))) break;
      }

      // ---- recurrent GEMM, this wave's K half: 8 sc loads in flight
      const u16* hb = h_buf + (t & 1) * (Bb * Hh) + bat * Hh + kbase + ko;
      v8s Ahh[8];
      #pragma unroll
      for (int s = 0; s < 8; ++s) {
        asm volatile("global_load_dwordx4 %0, %1, off offset:%c2 sc0 sc1"
                     : "=v"(Ahh[s]) : "v"(hb), "i"(s * 64));
      }
      asm volatile("s_waitcnt vmcnt(0)");
      #pragma unroll
      for (int s = 0; s < 8; ++s) {
        asm volatile("" : "+v"(Ahh[s]));
      }
      #pragma unroll
      for (int s = 0; s < 8; ++s) {
        #pragma unroll
        for (int rt = 0; rt < 8; ++rt)
          acc[rt] = MFMA(*(const v8s*)(Wh[rt] + s * 32), Ahh[s], acc[rt]);
      }
    }

    // ---- cross-wave K reduction through LDS
    if (wv == 1) {
      #pragma unroll
      for (int rt = 0; rt < 8; ++rt) red[rt * 64 + lane] = acc[rt];
    }
    __syncthreads();               // A: partials visible
    if (wv == 0) {
      #pragma unroll
      for (int rt = 0; rt < 8; ++rt) {
        v4f p = red[rt * 64 + lane];
        acc[rt][0] += p[0]; acc[rt][1] += p[1];
        acc[rt][2] += p[2]; acc[rt][3] += p[3];
      }
    }
    __syncthreads();               // B: red consumed -> wave 1 runs ahead

    if (wv == 0) {
      // ---- LSTM update in-register: tile rt = gate*2 + half;
      // lane owns batch bat, hidden jj = half*16 + q*4 + r.
      u16* hn = h_buf + ((t + 1) & 1) * (Bb * Hh) + bat * Hh + j0;
      #pragma unroll
      for (int hf = 0; hf < 2; ++hf) {
        u16 hv[4];
        #pragma unroll
        for (int r = 0; r < 4; ++r) {
          float ig = sigm  (acc[0 + hf][r] + bs[0][hf][r]);
          float fg = sigm  (acc[2 + hf][r] + bs[1][hf][r]);
          float gg = tanh_f(acc[4 + hf][r] + bs[2][hf][r]);
          float og = sigm  (acc[6 + hf][r] + bs[3][hf][r]);
          int ci = hf * 4 + r;
          cc[ci] = fg * cc[ci] + ig * gg;
          hv[r] = f2bf(og * tanh_f(cc[ci]));
        }
        v2u qv;
        qv[0] = (unsigned)hv[0] | ((unsigned)hv[1] << 16);
        qv[1] = (unsigned)hv[2] | ((unsigned)hv[3] << 16);
        u16* hp = hn + hf * 16 + q * 4;
        asm volatile("global_store_dwordx2 %0, %1, off sc0 sc1"
                     :: "v"(hp), "v"(qv) : "memory");
      }
      // publish: drain h stores (wave-wide), lane 0 sets flag (L3)
      asm volatile("s_waitcnt vmcnt(0)" ::: "memory");
      if (tid == 0) {
        unsigned tv = (unsigned)(t + 1);
        unsigned* fq = &fgrp[chunk];
        asm volatile("global_store_dword %0, %1, off sc0 sc1"
                     :: "v"(fq), "v"(tv) : "memory");
      }
    }
  }
}

// ---------------------------------------------------------------- epilogue:
// out[b] = h_last[b,:] . lin_w + lin_b   (h_last in h_buf[0], since T even)
__global__ void k_out(const u16* __restrict__ h, const float* __restrict__ lw,
                      const float* __restrict__ lb, float* __restrict__ out)
{
  int b = blockIdx.x * 64 + threadIdx.x;
  if (b >= Bb) return;
  const u16* hr = h + b * Hh;
  float acc = 0.f;
  #pragma unroll 8
  for (int k = 0; k < Hh; ++k) acc += bf2f(hr[k]) * lw[k];
  out[b] = acc + lb[0];
}

extern "C" void kernel_launch(void* const* d_in, const int* in_sizes, int n_in,
                              void* d_out, int out_size, void* d_ws, size_t ws_size,
                              hipStream_t stream)
{
  (void)in_sizes; (void)n_in; (void)out_size; (void)ws_size;
  const float* x       = (const float*)d_in[0];
  const float* wih_mu  = (const float*)d_in[1];
  const float* wih_rho = (const float*)d_in[2];
  const float* wih_eps = (const float*)d_in[3];
  const float* whh_mu  = (const float*)d_in[4];
  const float* whh_rho = (const float*)d_in[5];
  const float* whh_eps = (const float*)d_in[6];
  const float* b_mu    = (const float*)d_in[7];
  const float* b_rho   = (const float*)d_in[8];
  const float* b_eps   = (const float*)d_in[9];
  const float* lin_w   = (const float*)d_in[10];
  const float* lin_b   = (const float*)d_in[11];
  float* out = (float*)d_out;

  // workspace layout
  u16* x_bf  = (u16*)d_ws;                       // T*B*D bf16  = 16 MB
  u16* h_buf = x_bf + (size_t)Tt * Bb * Dd;      // 2*B*H bf16  = 512 KB
  unsigned* flags = (unsigned*)(h_buf + 2 * Bb * Hh);  // 256 flags

  k_prep<<<2048, 256, 0, stream>>>(x, x_bf, flags);

  hipFuncSetAttribute(reinterpret_cast<const void*>(lstm_main),
                      hipFuncAttributeMaxDynamicSharedMemorySize, SMEM_BYTES);
  lstm_main<<<NGROUP * NCHUNK, 128, SMEM_BYTES, stream>>>(
      whh_mu, whh_rho, whh_eps, wih_mu, wih_rho, wih_eps,
      b_mu, b_rho, b_eps, x_bf, h_buf, flags);

  k_out<<<(Bb + 63) / 64, 64, 0, stream>>>(h_buf, lin_w, lin_b, out);
}

// Round 10
// 2472.945 us; speedup vs baseline: 1.4389x; 1.2339x over previous
//
#include <hip/hip_runtime.h>

typedef unsigned short u16;
typedef unsigned long long u64;
typedef short v8s __attribute__((ext_vector_type(8)));
typedef float v4f __attribute__((ext_vector_type(4)));
typedef unsigned v2u __attribute__((ext_vector_type(2)));

#define Bb 256
#define Tt 512
#define Dd 64
#define Hh 512
#define G4 2048

#define NGROUP 16    // batch groups (16 batch each), static mapping
#define NCHUNK 16    // hidden chunks per group (32 hidden units each)
#define BT 16
#define HC 32
#define NCOL 128     // local gate cols = 4 gates * HC

#define WHH_S 520   // 512 + 8 pad (bf16 elems)
#define WIH_S 72    // 64 + 8 pad
#define SMEM_BYTES (NCOL*WHH_S*2 + NCOL*WIH_S*2)   // 151552 -> 1 block/CU

#define MFMA(a,b,c) __builtin_amdgcn_mfma_f32_16x16x32_bf16((a),(b),(c),0,0,0)

__device__ __forceinline__ u16 f2bf(float f) {
  unsigned u = __float_as_uint(f);
  unsigned r = (u + 0x7fffu + ((u >> 16) & 1u)) >> 16;
  return (u16)r;
}
__device__ __forceinline__ float bf2f(u16 v) {
  return __uint_as_float(((unsigned)v) << 16);
}
__device__ __forceinline__ float sigm(float x) { return 1.0f / (1.0f + __expf(-x)); }
__device__ __forceinline__ float tanh_f(float x) {
  float a = fabsf(x);
  float e = __expf(-2.0f * a);
  float r = (1.0f - e) / (1.0f + e);
  return copysignf(r, x);
}
__device__ __forceinline__ float softplus_f(float x) { return log1pf(__expf(x)); }

// ---------------------------------------------------------------- prep:
// x fp32 [B][T][D] -> bf16 [T][B][D]; zero 512 sync flags.
__global__ void k_prep(const float* __restrict__ x, u16* __restrict__ x_bf,
                       unsigned* __restrict__ flags)
{
  if (blockIdx.x < 2) {
    int i = blockIdx.x * 256 + threadIdx.x;
    if (i < NGROUP * NCHUNK * 2) flags[i] = 0u;
  }
  const int N4 = Tt * Bb * Dd / 4;
  int stride = gridDim.x * blockDim.x;
  for (int i = blockIdx.x * blockDim.x + threadIdx.x; i < N4; i += stride) {
    int idx = i * 4;
    int t = idx >> 14;          // / (B*D)
    int rem = idx & 16383;
    int b = rem >> 6;
    int d = rem & 63;
    float4 v = *(const float4*)(x + (size_t)b * (Tt * Dd) + t * Dd + d);
    unsigned lo = (unsigned)f2bf(v.x) | ((unsigned)f2bf(v.y) << 16);
    unsigned hi = (unsigned)f2bf(v.z) | ((unsigned)f2bf(v.w) << 16);
    *(uint2*)(x_bf + idx) = make_uint2(lo, hi);
  }
}

// ---------------------------------------------------------------- main:
// persistent LSTM. 256 blocks x 128 thr (2 waves), static group/chunk.
// GATE-SPLIT waves: wave wv owns hidden-half wv of the chunk -> tiles
// {g*2+wv}; each wave is a fully INDEPENDENT agent (own poll, own loads,
// own in-register update, own flag) -> ZERO intra-block barriers in the
// step loop. EVENT-DRIVEN consumption: 32 flags (2 lines) polled with one
// load; each ready (chunk,k-slice) is loaded + MFMA'd as it lands, with
// the next poll riding the same vmcnt drain. R9 BUG FIX: pv (poll result)
// must be register-tied AFTER the drain — inline-asm loads are invisible
// to compiler hazard tracking, so without the tie the ballot's v_cmp can
// be scheduled before the waitcnt and read garbage (caused absmax 0.41).
__global__ __launch_bounds__(128, 1) void lstm_main(
    const float* __restrict__ whh_mu, const float* __restrict__ whh_rho, const float* __restrict__ whh_eps,
    const float* __restrict__ wih_mu, const float* __restrict__ wih_rho, const float* __restrict__ wih_eps,
    const float* __restrict__ b_mu,  const float* __restrict__ b_rho,  const float* __restrict__ b_eps,
    const u16* __restrict__ x_bf, u16* __restrict__ h_buf, unsigned* __restrict__ flags)
{
  extern __shared__ char smem[];
  u16* w_hh_lds = (u16*)smem;                 // [NCOL][WHH_S]
  u16* w_ih_lds = w_hh_lds + NCOL * WHH_S;    // [NCOL][WIH_S]

  const int tid   = threadIdx.x;
  const int g     = blockIdx.x & 15;   // batch group (static)
  const int chunk = blockIdx.x >> 4;   // hidden chunk (static)
  const int b0    = g * BT;
  const int j0    = chunk * HC;

  // ---- sample weight chunk into LDS: one column per thread (128 cols)
  {
    const int lc = tid;                                // 0..127
    const int gcol = (lc >> 5) * Hh + j0 + (lc & 31);  // global gate column
    #pragma unroll 4
    for (int k = 0; k < Hh; ++k) {
      int gi = k * G4 + gcol;
      float w = whh_mu[gi] + softplus_f(whh_rho[gi]) * whh_eps[gi];
      w_hh_lds[lc * WHH_S + k] = f2bf(w);
    }
    #pragma unroll 4
    for (int k = 0; k < Dd; ++k) {
      int gi = k * G4 + gcol;
      float w = wih_mu[gi] + softplus_f(wih_rho[gi]) * wih_eps[gi];
      w_ih_lds[lc * WIH_S + k] = f2bf(w);
    }
  }

  // ---- geometry: wave wv owns hidden-half wv -> tiles rt = gate*2 + wv
  const int lane = tid & 63;
  const int wv   = tid >> 6;
  const int ln   = lane & 15;
  const int q    = lane >> 4;
  const int ko   = q * 8;

  const u16* WhP[4]; const u16* WxP[4];
  #pragma unroll
  for (int gt = 0; gt < 4; ++gt) {
    int rt = gt * 2 + wv;
    WhP[gt] = w_hh_lds + (rt * 16 + ln) * WHH_S + ko;
    WxP[gt] = w_ih_lds + (rt * 16 + ln) * WIH_S + ko;
  }

  const int bat = b0 + ln;   // this lane's batch row (B-operand col)

  // ---- per-lane biases: hidden jj = wv*16 + q*4 + r (4 units, all gates)
  float bs[4][4];
  #pragma unroll
  for (int gt = 0; gt < 4; ++gt)
    #pragma unroll
    for (int r = 0; r < 4; ++r) {
      int colg = gt * Hh + j0 + wv * 16 + q * 4 + r;
      bs[gt][r] = b_mu[colg] + softplus_f(b_rho[colg]) * b_eps[colg];
    }

  float cc[4] = {0.f, 0.f, 0.f, 0.f};
  // flags layout: fgrp2[w*16 + c] = flag of (chunk c, wave w) in group g
  unsigned* const fgrp2 = flags + g * (NCHUNK * 2);
  const unsigned* fp2 = fgrp2 + (lane & 31);
  __syncthreads();   // weights-in-LDS ready (one-time; only barrier used)

  for (int t = 0; t < Tt; ++t) {
    v4f ac0 = {0.f,0.f,0.f,0.f}, ac1 = {0.f,0.f,0.f,0.f};
    v4f ac2 = {0.f,0.f,0.f,0.f}, ac3 = {0.f,0.f,0.f,0.f};

    // ---- input projection (h-independent; overlaps first poll RTT)
    {
      const u16* xb = x_bf + (size_t)t * (Bb * Dd) + bat * Dd + ko;
      #pragma unroll
      for (int ks = 0; ks < 2; ++ks) {
        v8s xf = *(const v8s*)(xb + ks * 32);
        ac0 = MFMA(*(const v8s*)(WxP[0] + ks * 32), xf, ac0);
        ac1 = MFMA(*(const v8s*)(WxP[1] + ks * 32), xf, ac1);
        ac2 = MFMA(*(const v8s*)(WxP[2] + ks * 32), xf, ac2);
        ac3 = MFMA(*(const v8s*)(WxP[3] + ks * 32), xf, ac3);
      }
    }

    if (t > 0) {
      // ---- event-driven recurrent GEMM: consume 32-k slices as their
      // producers' flags land; next poll rides the same vmcnt drain.
      const u16* hb = h_buf + (t & 1) * (Bb * Hh) + bat * Hh + ko;
      unsigned done = 0, todo = 0;
      v8s buf[16];
      for (;;) {
        unsigned pv = 0;
        bool needPoll = (done | todo) != 0xFFFFu;
        if (needPoll) {
          asm volatile("global_load_dword %0, %1, off sc0 sc1"
                       : "=v"(pv) : "v"(fp2));
        }
        #pragma unroll
        for (int c = 0; c < 16; ++c)
          if (todo & (1u << c)) {
            asm volatile("global_load_dwordx4 %0, %1, off offset:%c2 sc0 sc1"
                         : "=v"(buf[c]) : "v"(hb), "i"(c * 64));
          }
        asm volatile("s_waitcnt vmcnt(0)");
        // R9 fix: pin pv's availability after the drain (see header note)
        if (needPoll) {
          asm volatile("" : "+v"(pv));
        }
        #pragma unroll
        for (int c = 0; c < 16; ++c)
          if (todo & (1u << c)) {
            asm volatile("" : "+v"(buf[c]));
            ac0 = MFMA(*(const v8s*)(WhP[0] + c * 32), buf[c], ac0);
            ac1 = MFMA(*(const v8s*)(WhP[1] + c * 32), buf[c], ac1);
            ac2 = MFMA(*(const v8s*)(WhP[2] + c * 32), buf[c], ac2);
            ac3 = MFMA(*(const v8s*)(WhP[3] + c * 32), buf[c], ac3);
          }
        done |= todo;
        if (done == 0xFFFFu) break;
        u64 bal = __ballot((int)(pv >= (unsigned)t));
        unsigned lo = (unsigned)bal;
        unsigned ready = lo & (lo >> 16) & 0xFFFFu;   // both waves of chunk c
        todo = ready & ~done;
      }
    }

    // ---- LSTM update fully in-register; one 8B sc store of this wave's
    // 4 hidden units for batch bat.
    {
      u16 hv[4];
      #pragma unroll
      for (int r = 0; r < 4; ++r) {
        float ig = sigm  (ac0[r] + bs[0][r]);
        float fg = sigm  (ac1[r] + bs[1][r]);
        float gg = tanh_f(ac2[r] + bs[2][r]);
        float og = sigm  (ac3[r] + bs[3][r]);
        cc[r] = fg * cc[r] + ig * gg;
        hv[r] = f2bf(og * tanh_f(cc[r]));
      }
      v2u qv;
      qv[0] = (unsigned)hv[0] | ((unsigned)hv[1] << 16);
      qv[1] = (unsigned)hv[2] | ((unsigned)hv[3] << 16);
      u16* hp = h_buf + ((t + 1) & 1) * (Bb * Hh) + bat * Hh
              + j0 + wv * 16 + q * 4;
      asm volatile("global_store_dwordx2 %0, %1, off sc0 sc1"
                   :: "v"(hp), "v"(qv) : "memory");
    }

    // ---- publish (per wave, independent): drain h stores, set own flag
    asm volatile("s_waitcnt vmcnt(0)" ::: "memory");
    if (lane == 0) {
      unsigned tv = (unsigned)(t + 1);
      unsigned* fq = &fgrp2[wv * 16 + chunk];
      asm volatile("global_store_dword %0, %1, off sc0 sc1"
                   :: "v"(fq), "v"(tv) : "memory");
    }
  }
}

// ---------------------------------------------------------------- epilogue:
// out[b] = h_last[b,:] . lin_w + lin_b   (h_last in h_buf[0], since T even)
__global__ void k_out(const u16* __restrict__ h, const float* __restrict__ lw,
                      const float* __restrict__ lb, float* __restrict__ out)
{
  int b = blockIdx.x * 64 + threadIdx.x;
  if (b >= Bb) return;
  const u16* hr = h + b * Hh;
  float acc = 0.f;
  #pragma unroll 8
  for (int k = 0; k < Hh; ++k) acc += bf2f(hr[k]) * lw[k];
  out[b] = acc + lb[0];
}

extern "C" void kernel_launch(void* const* d_in, const int* in_sizes, int n_in,
                              void* d_out, int out_size, void* d_ws, size_t ws_size,
                              hipStream_t stream)
{
  (void)in_sizes; (void)n_in; (void)out_size; (void)ws_size;
  const float* x       = (const float*)d_in[0];
  const float* wih_mu  = (const float*)d_in[1];
  const float* wih_rho = (const float*)d_in[2];
  const float* wih_eps = (const float*)d_in[3];
  const float* whh_mu  = (const float*)d_in[4];
  const float* whh_rho = (const float*)d_in[5];
  const float* whh_eps = (const float*)d_in[6];
  const float* b_mu    = (const float*)d_in[7];
  const float* b_rho   = (const float*)d_in[8];
  const float* b_eps   = (const float*)d_in[9];
  const float* lin_w   = (const float*)d_in[10];
  const float* lin_b   = (const float*)d_in[11];
  float* out = (float*)d_out;

  // workspace layout
  u16* x_bf  = (u16*)d_ws;                       // T*B*D bf16  = 16 MB
  u16* h_buf = x_bf + (size_t)Tt * Bb * Dd;      // 2*B*H bf16  = 512 KB
  unsigned* flags = (unsigned*)(h_buf + 2 * Bb * Hh);  // 512 flags

  k_prep<<<2048, 256, 0, stream>>>(x, x_bf, flags);

  hipFuncSetAttribute(reinterpret_cast<const void*>(lstm_main),
                      hipFuncAttributeMaxDynamicSharedMemorySize, SMEM_BYTES);
  lstm_main<<<NGROUP * NCHUNK, 128, SMEM_BYTES, stream>>>(
      whh_mu, whh_rho, whh_eps, wih_mu, wih_rho, wih_eps,
      b_mu, b_rho, b_eps, x_bf, h_buf, flags);

  k_out<<<(Bb + 63) / 64, 64, 0, stream>>>(h_buf, lin_w, lin_b, out);
}